// Round 9
// baseline (395.747 us; speedup 1.0000x reference)
//
#include <hip/hip_runtime.h>
#include <math.h>

// ---------------------------------------------------------------------------
// GCN link prediction. bf16 node tables + bf16 MFMA, fp32 accumulate.
// Counting-sort CSR (atomic-free). Round-9: k_edge processes CSR-by-dst
// order (round-7 measured 119 MB fetch vs 199 original-order) and writes
// scores COALESCED to tmp[pos]; a dedicated k_perm scatters out[eidx[p]] =
// tmp[p] with no concurrent read pressure (out fits in aggregate L2 ->
// bounded write amplification). Round-8's byte-neutral k_edge trade undone.
// k_agg keeps the round-8 thread-group-per-node design (16 rows in flight).
// ---------------------------------------------------------------------------

#define NBLK 256
#define NBUK 512
#define GRD (NBUK * NBLK)
#define GRT (2 * GRD)

typedef __attribute__((ext_vector_type(8))) short bf16x8;
typedef __attribute__((ext_vector_type(4))) float f32x4;

__device__ __forceinline__ float bl(unsigned u) { return __uint_as_float(u << 16); }
__device__ __forceinline__ float bh(unsigned u) { return __uint_as_float(u & 0xffff0000u); }
__device__ __forceinline__ unsigned short f2bf(float f) {
  unsigned u = __float_as_uint(f);
  return (unsigned short)((u + 0x7fffu + ((u >> 16) & 1u)) >> 16);
}
__device__ __forceinline__ unsigned packbf2(float a, float b) {
  return (unsigned)f2bf(a) | ((unsigned)f2bf(b) << 16);
}

// ---- CSR build (counting sort) + weight prep --------------------------------

__global__ __launch_bounds__(256) void k_hist(
    const int* __restrict__ src, const int* __restrict__ dst,
    int* __restrict__ grams, int E,
    const float* __restrict__ W1, const float* __restrict__ W2,
    const float* __restrict__ Wp1, const float* __restrict__ Wp2,
    unsigned short* __restrict__ W1t, unsigned short* __restrict__ W2t,
    unsigned short* __restrict__ Wct, unsigned short* __restrict__ Wp2t) {
  __shared__ int hd[NBUK], hs[NBUK];
  int blk = blockIdx.x, t = threadIdx.x;
  {
    int i = blk * 256 + t;
    if (i < 16384) {
      int n = i >> 7, k = i & 127;
      W1t[i] = f2bf(W1[k * 128 + n]);
    } else if (i < 24576) {
      int j = i - 16384; int n = j >> 7, k = j & 127;
      W2t[j] = f2bf(W2[k * 64 + n]);
    } else if (i < 32768) {
      int j = i - 24576; int c = j >> 6, k = j & 63;
      float v = (c < 64) ? Wp1[k * 64 + c] : Wp1[(k + 64) * 64 + (c - 64)];
      Wct[j] = f2bf(v);
    } else if (i < 34816) {
      int j = i - 32768; int n = j >> 6, k = j & 63;
      Wp2t[j] = f2bf(Wp2[k * 32 + n]);
    }
  }
  for (int k = t; k < NBUK; k += 256) { hd[k] = 0; hs[k] = 0; }
  __syncthreads();
  int chunk = (E + NBLK - 1) / NBLK;
  int start = blk * chunk, end = min(E, start + chunk);
  for (int i = start + t; i < end; i += 256) {
    atomicAdd(&hd[dst[i] >> 8], 1);
    atomicAdd(&hs[src[i] >> 8], 1);
  }
  __syncthreads();
  for (int k = t; k < NBUK; k += 256) {
    grams[k * NBLK + blk] = hd[k];
    grams[GRD + k * NBLK + blk] = hs[k];
  }
}

__global__ __launch_bounds__(256) void k_gscan1(const int* __restrict__ g,
                                                int* __restrict__ bsum) {
  __shared__ int lds[256];
  int b = blockIdx.x, t = threadIdx.x;
  int base = b * 1024 + t * 4;
  int s = g[base] + g[base + 1] + g[base + 2] + g[base + 3];
  lds[t] = s; __syncthreads();
  for (int st = 128; st > 0; st >>= 1) {
    if (t < st) lds[t] += lds[t + st];
    __syncthreads();
  }
  if (t == 0) bsum[b] = lds[0];
}

__global__ __launch_bounds__(256) void k_gscan3(int* __restrict__ g,
                                                const int* __restrict__ bsum) {
  __shared__ int lds[256], lds2[256];
  int b = blockIdx.x, t = threadIdx.x;
  int bv = bsum[t];
  lds2[t] = bv; __syncthreads();
  for (int st = 1; st < 256; st <<= 1) {
    int add = (t >= st) ? lds2[t - st] : 0;
    __syncthreads();
    lds2[t] += add;
    __syncthreads();
  }
  int bpref = (b > 0) ? lds2[b - 1] : 0;

  int base = b * 1024 + t * 4;
  int v[4]; int s = 0;
#pragma unroll
  for (int j = 0; j < 4; j++) { v[j] = g[base + j]; s += v[j]; }
  lds[t] = s; __syncthreads();
  int mine = s;
  for (int st = 1; st < 256; st <<= 1) {
    int add = (t >= st) ? lds[t - st] : 0;
    __syncthreads();
    lds[t] += add;
    __syncthreads();
  }
  int excl = lds[t] - mine + bpref;
#pragma unroll
  for (int j = 0; j < 4; j++) { g[base + j] = excl; excl += v[j]; }
}

__global__ __launch_bounds__(256) void k_part(
    const int* __restrict__ src, const int* __restrict__ dst,
    const int* __restrict__ grams, uint2* __restrict__ pdst,
    unsigned char* __restrict__ sbuf, int E) {
  __shared__ int curd[NBUK], curs[NBUK];
  int blk = blockIdx.x, t = threadIdx.x;
  for (int k = t; k < NBUK; k += 256) {
    curd[k] = grams[k * NBLK + blk];
    curs[k] = grams[GRD + k * NBLK + blk] - E;
  }
  __syncthreads();
  int chunk = (E + NBLK - 1) / NBLK;
  int start = blk * chunk, end = min(E, start + chunk);
  for (int i = start + t; i < end; i += 256) {
    int s = src[i], d = dst[i];
    int pd = atomicAdd(&curd[d >> 8], 1);
    pdst[pd] = make_uint2((unsigned)s, (unsigned)i | ((unsigned)(d & 255) << 21));
    int ps = atomicAdd(&curs[s >> 8], 1);
    sbuf[ps] = (unsigned char)(s & 255);
  }
}

__global__ __launch_bounds__(256) void k_dcsr(
    const uint2* __restrict__ pdst, const unsigned char* __restrict__ sbuf,
    const int* __restrict__ grams,
    int* __restrict__ adj, int* __restrict__ dnode, int* __restrict__ eidx,
    int* __restrict__ rowst, float* __restrict__ rin, float* __restrict__ rout,
    int N, int E) {
  __shared__ int hist[256], cur[256];
  int b = blockIdx.x, t = threadIdx.x;
  int base = grams[b * 256];
  int end  = grams[b * 256 + 256];
  hist[t] = 0; __syncthreads();
  for (int i = base + t; i < end; i += 256)
    atomicAdd(&hist[(pdst[i].y >> 21) & 255], 1);
  __syncthreads();
  int cnt = hist[t];
  for (int st = 1; st < 256; st <<= 1) {
    int add = (t >= st) ? hist[t - st] : 0;
    __syncthreads();
    hist[t] += add;
    __syncthreads();
  }
  int excl = hist[t] - cnt;
  cur[t] = excl;
  int node = b * 256 + t;
  if (node < N) {
    rowst[node] = base + excl;
    rin[node] = rsqrtf((float)max(cnt, 1));
  }
  __syncthreads();
  for (int i = base + t; i < end; i += 256) {
    uint2 u = pdst[i];
    int lo = (u.y >> 21) & 255;
    int eid = (int)(u.y & 0x1FFFFFu);
    int pos = base + atomicAdd(&cur[lo], 1);
    adj[pos] = (int)u.x;
    dnode[pos] = b * 256 + lo;
    eidx[pos] = eid;
  }
  __syncthreads();
  hist[t] = 0; __syncthreads();
  int sb = grams[GRD + b * 256] - E;
  int se = grams[GRD + b * 256 + 256] - E;
  for (int i = sb + t; i < se; i += 256)
    atomicAdd(&hist[sbuf[i]], 1);
  __syncthreads();
  if (node < N) rout[node] = rsqrtf((float)max(hist[t], 1));
}

// ---- MFMA GEMM: C_bf16[M,BN] = (A[M,K]*scale[M]?) @ W[K,BN], Wt bf16 [BN][K]
template <int K, int BN, bool ABF, bool SC>
__global__ __launch_bounds__(256) void k_gemm(
    const void* __restrict__ Av, const float* __restrict__ scale,
    const unsigned short* __restrict__ Wt, unsigned short* __restrict__ C, int M) {
  constexpr int KP = K + 8;
  __shared__ __attribute__((aligned(16))) unsigned short As[64][KP];
  __shared__ __attribute__((aligned(16))) unsigned short Ws[BN][KP];
  int tid = threadIdx.x;
  int row0 = blockIdx.x * 64;

  for (int i = tid; i < BN * K / 8; i += 256) {
    int n = i / (K / 8), seg = i % (K / 8);
    *(uint4*)&Ws[n][seg * 8] = ((const uint4*)Wt)[i];
  }
  {
    constexpr int CH = K / 4;
    int r = tid >> 2, q = tid & 3;
    int row = row0 + r;
    if (row < M) {
      float sc = SC ? scale[row] : 1.0f;
      if constexpr (!ABF) {
        const float4* ap = (const float4*)((const float*)Av + (size_t)row * K + q * CH);
#pragma unroll
        for (int c = 0; c < CH / 8; c++) {
          float4 v0 = ap[2 * c], v1 = ap[2 * c + 1];
          uint4 o;
          o.x = packbf2(v0.x * sc, v0.y * sc);
          o.y = packbf2(v0.z * sc, v0.w * sc);
          o.z = packbf2(v1.x * sc, v1.y * sc);
          o.w = packbf2(v1.z * sc, v1.w * sc);
          *(uint4*)&As[r][q * CH + c * 8] = o;
        }
      } else {
        const uint4* ap = (const uint4*)((const unsigned short*)Av + (size_t)row * K + q * CH);
#pragma unroll
        for (int c = 0; c < CH / 8; c++) {
          uint4 v = ap[c];
          if constexpr (SC) {
            uint4 o;
            o.x = packbf2(bl(v.x) * sc, bh(v.x) * sc);
            o.y = packbf2(bl(v.y) * sc, bh(v.y) * sc);
            o.z = packbf2(bl(v.z) * sc, bh(v.z) * sc);
            o.w = packbf2(bl(v.w) * sc, bh(v.w) * sc);
            *(uint4*)&As[r][q * CH + c * 8] = o;
          } else {
            *(uint4*)&As[r][q * CH + c * 8] = v;
          }
        }
      }
    } else {
#pragma unroll
      for (int c = 0; c < CH / 8; c++)
        *(uint4*)&As[r][q * CH + c * 8] = make_uint4(0, 0, 0, 0);
    }
  }
  __syncthreads();

  constexpr int KS = K / 32;
  constexpr int NT = BN / 16;
  int wav = tid >> 6, lane = tid & 63;
  int quad = lane >> 4, lrow = lane & 15;
  int mb = wav * 16;

  bf16x8 af[KS];
#pragma unroll
  for (int s = 0; s < KS; s++)
    af[s] = *(const bf16x8*)&As[mb + lrow][s * 32 + quad * 8];

  f32x4 acc[NT];
#pragma unroll
  for (int nt = 0; nt < NT; nt++) acc[nt] = (f32x4){0.f, 0.f, 0.f, 0.f};
#pragma unroll
  for (int nt = 0; nt < NT; nt++) {
#pragma unroll
    for (int s = 0; s < KS; s++) {
      bf16x8 bf = *(const bf16x8*)&Ws[nt * 16 + lrow][s * 32 + quad * 8];
      acc[nt] = __builtin_amdgcn_mfma_f32_16x16x32_bf16(af[s], bf, acc[nt], 0, 0, 0);
    }
  }
#pragma unroll
  for (int nt = 0; nt < NT; nt++) {
#pragma unroll
    for (int reg = 0; reg < 4; reg++) {
      int row = row0 + mb + quad * 4 + reg;
      if (row < M) C[(size_t)row * BN + nt * 16 + lrow] = f2bf(acc[nt][reg]);
    }
  }
}

// ---- aggregation: TPN threads per node, each owns a uint4 (8 bf16) chunk ----
template <int F>
__global__ __launch_bounds__(256) void k_agg(
    const unsigned short* __restrict__ hin, const int* __restrict__ rowst,
    const int* __restrict__ adj, const float* __restrict__ rin,
    const float* __restrict__ bias, unsigned short* __restrict__ hout,
    int N, int E, int do_relu) {
  constexpr int TPN = F / 8;
  constexpr int NPB = 256 / TPN;
  int node = blockIdx.x * NPB + threadIdx.x / TPN;
  int c = threadIdx.x % TPN;
  if (node >= N) return;
  int start = rowst[node];
  int end = (node + 1 < N) ? rowst[node + 1] : E;
  const uint4* h4 = (const uint4*)hin;

  float a[8], b[8];
#pragma unroll
  for (int j = 0; j < 8; j++) { a[j] = 0.f; b[j] = 0.f; }

  int i = start;
  for (; i + 3 < end; i += 4) {
    uint4 w0 = h4[(size_t)adj[i] * TPN + c];
    uint4 w1 = h4[(size_t)adj[i + 1] * TPN + c];
    uint4 w2 = h4[(size_t)adj[i + 2] * TPN + c];
    uint4 w3 = h4[(size_t)adj[i + 3] * TPN + c];
    a[0] += bl(w0.x); a[1] += bh(w0.x); a[2] += bl(w0.y); a[3] += bh(w0.y);
    a[4] += bl(w0.z); a[5] += bh(w0.z); a[6] += bl(w0.w); a[7] += bh(w0.w);
    b[0] += bl(w1.x); b[1] += bh(w1.x); b[2] += bl(w1.y); b[3] += bh(w1.y);
    b[4] += bl(w1.z); b[5] += bh(w1.z); b[6] += bl(w1.w); b[7] += bh(w1.w);
    a[0] += bl(w2.x); a[1] += bh(w2.x); a[2] += bl(w2.y); a[3] += bh(w2.y);
    a[4] += bl(w2.z); a[5] += bh(w2.z); a[6] += bl(w2.w); a[7] += bh(w2.w);
    b[0] += bl(w3.x); b[1] += bh(w3.x); b[2] += bl(w3.y); b[3] += bh(w3.y);
    b[4] += bl(w3.z); b[5] += bh(w3.z); b[6] += bl(w3.w); b[7] += bh(w3.w);
  }
  for (; i < end; i++) {
    uint4 w0 = h4[(size_t)adj[i] * TPN + c];
    a[0] += bl(w0.x); a[1] += bh(w0.x); a[2] += bl(w0.y); a[3] += bh(w0.y);
    a[4] += bl(w0.z); a[5] += bh(w0.z); a[6] += bl(w0.w); a[7] += bh(w0.w);
  }
  float r = rin[node];
  const float4* bp = (const float4*)(bias + c * 8);
  float4 bb0 = bp[0], bb1 = bp[1];
  float o0 = fmaf(a[0] + b[0], r, bb0.x);
  float o1 = fmaf(a[1] + b[1], r, bb0.y);
  float o2 = fmaf(a[2] + b[2], r, bb0.z);
  float o3 = fmaf(a[3] + b[3], r, bb0.w);
  float o4 = fmaf(a[4] + b[4], r, bb1.x);
  float o5 = fmaf(a[5] + b[5], r, bb1.y);
  float o6 = fmaf(a[6] + b[6], r, bb1.z);
  float o7 = fmaf(a[7] + b[7], r, bb1.w);
  if (do_relu) {
    o0 = fmaxf(o0, 0.f); o1 = fmaxf(o1, 0.f); o2 = fmaxf(o2, 0.f);
    o3 = fmaxf(o3, 0.f); o4 = fmaxf(o4, 0.f); o5 = fmaxf(o5, 0.f);
    o6 = fmaxf(o6, 0.f); o7 = fmaxf(o7, 0.f);
  }
  uint4 o;
  o.x = packbf2(o0, o1); o.y = packbf2(o2, o3);
  o.z = packbf2(o4, o5); o.w = packbf2(o6, o7);
  ((uint4*)hout)[(size_t)node * TPN + c] = o;
}

// ---- per-edge MLP, CSR order, coalesced tmp writes --------------------------
__global__ __launch_bounds__(256) void k_edge(
    const unsigned short* __restrict__ ab, const int* __restrict__ adj,
    const int* __restrict__ dnode,
    const unsigned short* __restrict__ Wp2t, const float* __restrict__ bp1,
    const float* __restrict__ bp2, const float* __restrict__ Wp3,
    const float* __restrict__ bp3, float* __restrict__ tmp, int E) {
  __shared__ __attribute__((aligned(16))) unsigned short z1s[128][72];
  __shared__ __attribute__((aligned(16))) unsigned short w2t[32][72];
  __shared__ float sb1[64], sb2[32], sw3[32];

  int t = threadIdx.x;
  {
    uint4 v = ((const uint4*)Wp2t)[t];
    int n = t >> 3, seg = t & 7;
    *(uint4*)&w2t[n][seg * 8] = v;
    if (t < 64) sb1[t] = bp1[t];
    else if (t < 96) sb2[t - 64] = bp2[t - 64];
    else if (t < 128) sw3[t - 96] = Wp3[t - 96];
  }
  __syncthreads();

  int p0 = blockIdx.x * 128;
  {
    int m = t >> 1, half = t & 1, p = p0 + m;
    int s = 0, d = 0;
    if (p < E) { s = adj[p]; d = dnode[p]; }
    const uint4* apf = (const uint4*)(ab + (size_t)s * 128 + half * 32);
    const uint4* bpf = (const uint4*)(ab + (size_t)d * 128 + 64 + half * 32);
    int jb = half * 32;
#pragma unroll
    for (int q = 0; q < 4; q++) {
      uint4 av = apf[q], bv = bpf[q];
      int j = jb + 8 * q;
      float z0 = fmaxf(bl(av.x) + bl(bv.x) + sb1[j + 0], 0.f);
      float z1 = fmaxf(bh(av.x) + bh(bv.x) + sb1[j + 1], 0.f);
      float z2 = fmaxf(bl(av.y) + bl(bv.y) + sb1[j + 2], 0.f);
      float z3 = fmaxf(bh(av.y) + bh(bv.y) + sb1[j + 3], 0.f);
      float z4 = fmaxf(bl(av.z) + bl(bv.z) + sb1[j + 4], 0.f);
      float z5 = fmaxf(bh(av.z) + bh(bv.z) + sb1[j + 5], 0.f);
      float z6 = fmaxf(bl(av.w) + bl(bv.w) + sb1[j + 6], 0.f);
      float z7 = fmaxf(bh(av.w) + bh(bv.w) + sb1[j + 7], 0.f);
      uint4 o;
      o.x = packbf2(z0, z1); o.y = packbf2(z2, z3);
      o.z = packbf2(z4, z5); o.w = packbf2(z6, z7);
      *(uint4*)&z1s[m][j] = o;
    }
  }
  __syncthreads();

  int wav = t >> 6, lane = t & 63;
  int quad = lane >> 4, lrow = lane & 15;

  bf16x8 bfr[2][2];
#pragma unroll
  for (int s = 0; s < 2; s++)
#pragma unroll
    for (int nt = 0; nt < 2; nt++)
      bfr[s][nt] = *(const bf16x8*)&w2t[nt * 16 + lrow][s * 32 + quad * 8];

  f32x4 acc[2][2];
#pragma unroll
  for (int mt = 0; mt < 2; mt++)
#pragma unroll
    for (int nt = 0; nt < 2; nt++) acc[mt][nt] = (f32x4){0.f, 0.f, 0.f, 0.f};

#pragma unroll
  for (int mt = 0; mt < 2; mt++) {
    int mb = (wav * 2 + mt) * 16;
#pragma unroll
    for (int s = 0; s < 2; s++) {
      bf16x8 a = *(const bf16x8*)&z1s[mb + lrow][s * 32 + quad * 8];
#pragma unroll
      for (int nt = 0; nt < 2; nt++)
        acc[mt][nt] = __builtin_amdgcn_mfma_f32_16x16x32_bf16(a, bfr[s][nt], acc[mt][nt], 0, 0, 0);
    }
  }

  float bb0 = sb2[lrow], bb1 = sb2[16 + lrow];
  float w30 = sw3[lrow], w31 = sw3[16 + lrow];
  float p2[2][4];
#pragma unroll
  for (int mt = 0; mt < 2; mt++)
#pragma unroll
    for (int reg = 0; reg < 4; reg++)
      p2[mt][reg] = fmaxf(acc[mt][0][reg] + bb0, 0.f) * w30 +
                    fmaxf(acc[mt][1][reg] + bb1, 0.f) * w31;
#pragma unroll
  for (int off = 1; off < 16; off <<= 1) {
#pragma unroll
    for (int mt = 0; mt < 2; mt++)
#pragma unroll
      for (int reg = 0; reg < 4; reg++)
        p2[mt][reg] += __shfl_xor(p2[mt][reg], off, 64);
  }
  if (lrow < 4) {
    float b3 = bp3[0];
#pragma unroll
    for (int mt = 0; mt < 2; mt++) {
      float score = p2[mt][0];
      if (lrow == 1) score = p2[mt][1];
      if (lrow == 2) score = p2[mt][2];
      if (lrow == 3) score = p2[mt][3];
      score += b3;
      int pp = p0 + (wav * 2 + mt) * 16 + quad * 4 + lrow;
      if (pp < E) tmp[pp] = 1.0f / (1.0f + __expf(-score));
    }
  }
}

// dedicated scatter: out[eidx[p]] = tmp[p]. Coalesced reads; out fits in
// aggregate L2, no concurrent read pressure -> bounded write amplification.
__global__ __launch_bounds__(256) void k_perm(
    const float* __restrict__ tmp, const int* __restrict__ eidx,
    float* __restrict__ out, int E) {
  int p = blockIdx.x * 256 + threadIdx.x;
  if (p < E) out[eidx[p]] = tmp[p];
}

extern "C" void kernel_launch(void* const* d_in, const int* in_sizes, int n_in,
                              void* d_out, int out_size, void* d_ws, size_t ws_size,
                              hipStream_t stream) {
  const float* x   = (const float*)d_in[0];
  const int*   src = (const int*)d_in[1];
  const int*   dst = (const int*)d_in[2];
  const float* W1  = (const float*)d_in[3];
  const float* b1  = (const float*)d_in[4];
  const float* W2  = (const float*)d_in[5];
  const float* b2  = (const float*)d_in[6];
  const float* Wp1 = (const float*)d_in[7];
  const float* bp1 = (const float*)d_in[8];
  const float* Wp2 = (const float*)d_in[9];
  const float* bp2 = (const float*)d_in[10];
  const float* Wp3 = (const float*)d_in[11];
  const float* bp3 = (const float*)d_in[12];
  float* out = (float*)d_out;

  int N = in_sizes[0] / 128;
  int E = in_sizes[1];

  char* w = (char*)d_ws;
  unsigned short* bufA = (unsigned short*)w;          // aliases pdst+sbuf
  uint2* pdst = (uint2*)w;                            // E*8 (alias)
  unsigned char* sbuf = (unsigned char*)(w + (size_t)E * 8);  // E*1 (alias)
  w += (size_t)N * 128 * 2;
  unsigned short* bufB = (unsigned short*)w;          // h1/h; tmp aliases it
  float* tmp = (float*)bufB;                          // (bufB dead at k_edge)
  w += (size_t)N * 128 * 2;
  int* grams  = (int*)w;    w += (size_t)GRT * sizeof(int);
  int* bsum   = (int*)w;    w += 256 * sizeof(int);
  int* rowst  = (int*)w;    w += (size_t)N * sizeof(int);
  int* adj    = (int*)w;    w += (size_t)E * sizeof(int);
  int* dnode  = (int*)w;    w += (size_t)E * sizeof(int);
  int* eidx   = (int*)w;    w += (size_t)E * sizeof(int);
  float* rin  = (float*)w;  w += (size_t)N * sizeof(float);
  float* rout = (float*)w;  w += (size_t)N * sizeof(float);
  unsigned short* W1t  = (unsigned short*)w; w += 16384 * 2;
  unsigned short* W2t  = (unsigned short*)w; w += 8192 * 2;
  unsigned short* Wct  = (unsigned short*)w; w += 8192 * 2;
  unsigned short* Wp2t = (unsigned short*)w; w += 2048 * 2;

  int nbk = (N + 255) / 256;

  // ---- CSR build + weight prep ----
  k_hist<<<NBLK, 256, 0, stream>>>(src, dst, grams, E, W1, W2, Wp1, Wp2,
                                   W1t, W2t, Wct, Wp2t);
  k_gscan1<<<GRT / 1024, 256, 0, stream>>>(grams, bsum);
  k_gscan3<<<GRT / 1024, 256, 0, stream>>>(grams, bsum);
  k_part<<<NBLK, 256, 0, stream>>>(src, dst, grams, pdst, sbuf, E);
  k_dcsr<<<nbk, 256, 0, stream>>>(pdst, sbuf, grams, adj, dnode, eidx,
                                  rowst, rin, rout, N, E);

  // ---- dense pipeline ----
  // h0 = bf16((x*rout)@W1) -> bufA [N,128]
  k_gemm<128, 128, false, true><<<(N + 63) / 64, 256, 0, stream>>>(x, rout, W1t, bufA, N);
  // h1 = relu(Agg(h0)*rin + b1) -> bufB [N,128]
  k_agg<128><<<(N + 15) / 16, 256, 0, stream>>>(bufA, rowst, adj, rin, b1, bufB, N, E, 1);
  // h2p = bf16((h1*rout)@W2) -> bufA [N,64]
  k_gemm<128, 64, true, true><<<(N + 63) / 64, 256, 0, stream>>>(bufB, rout, W2t, bufA, N);
  // h = Agg(h2p)*rin + b2 -> bufB [N,64]  (only first N*64 of bufB used)
  k_agg<64><<<(N + 31) / 32, 256, 0, stream>>>(bufA, rowst, adj, rin, b2, bufB, N, E, 0);
  // ab = bf16(h @ Wc) -> bufA [N,128]
  k_gemm<64, 128, true, false><<<(N + 63) / 64, 256, 0, stream>>>(bufB, nullptr, Wct, bufA, N);
  // edge MLP + sigmoid, CSR order, coalesced tmp writes
  // tmp aliases bufB upper half: place tmp AFTER the live h region? bufB's
  // first N*64 shorts hold h, which is dead once k_gemm(ab) completes —
  // k_edge runs after, so the whole bufB region is free. tmp = bufB base.
  k_edge<<<(E + 127) / 128, 256, 0, stream>>>(bufA, adj, dnode, Wp2t,
                                              bp1, bp2, Wp3, bp3, tmp, E);
  // scatter to original edge order
  k_perm<<<(E + 255) / 256, 256, 0, stream>>>(tmp, eidx, out, E);
}

// Round 10
// 374.857 us; speedup vs baseline: 1.0557x; 1.0557x over previous
//
#include <hip/hip_runtime.h>
#include <math.h>

// ---------------------------------------------------------------------------
// GCN link prediction. bf16 node tables + bf16 MFMA, fp32 accumulate.
// Counting-sort CSR (atomic-free, slim). Round-10 (base = round-8 best):
//  - k_edge: original edge order, coalesced NONTEMPORAL out stores (round-8
//    showed 106 MB write traffic for a 6.4 MB never-re-read output).
//  - rout deferred from gemm1 into agg1 (broadcast rout[adj[i]] FMA), which
//    breaks the gemm1->dcsr dependency; dcsr FUSED into gemm1's launch
//    (k_gdc, block-uniform branch) so the build tail hides under the GEMM.
//  - k_agg keeps round-8 thread-group-per-node design (at compulsory-miss
//    floor, 3.43 TB/s measured round-9).
// ---------------------------------------------------------------------------

#define NBLK 256
#define NBUK 512
#define GRD (NBUK * NBLK)
#define GRT (2 * GRD)

typedef __attribute__((ext_vector_type(8))) short bf16x8;
typedef __attribute__((ext_vector_type(4))) float f32x4;

__device__ __forceinline__ float bl(unsigned u) { return __uint_as_float(u << 16); }
__device__ __forceinline__ float bh(unsigned u) { return __uint_as_float(u & 0xffff0000u); }
__device__ __forceinline__ unsigned short f2bf(float f) {
  unsigned u = __float_as_uint(f);
  return (unsigned short)((u + 0x7fffu + ((u >> 16) & 1u)) >> 16);
}
__device__ __forceinline__ unsigned packbf2(float a, float b) {
  return (unsigned)f2bf(a) | ((unsigned)f2bf(b) << 16);
}

// ---- CSR build (counting sort) + weight prep --------------------------------

__global__ __launch_bounds__(256) void k_hist(
    const int* __restrict__ src, const int* __restrict__ dst,
    int* __restrict__ grams, int E,
    const float* __restrict__ W1, const float* __restrict__ W2,
    const float* __restrict__ Wp1, const float* __restrict__ Wp2,
    unsigned short* __restrict__ W1t, unsigned short* __restrict__ W2t,
    unsigned short* __restrict__ Wct, unsigned short* __restrict__ Wp2t) {
  __shared__ int hd[NBUK], hs[NBUK];
  int blk = blockIdx.x, t = threadIdx.x;
  {
    int i = blk * 256 + t;
    if (i < 16384) {
      int n = i >> 7, k = i & 127;
      W1t[i] = f2bf(W1[k * 128 + n]);
    } else if (i < 24576) {
      int j = i - 16384; int n = j >> 7, k = j & 127;
      W2t[j] = f2bf(W2[k * 64 + n]);
    } else if (i < 32768) {
      int j = i - 24576; int c = j >> 6, k = j & 63;
      float v = (c < 64) ? Wp1[k * 64 + c] : Wp1[(k + 64) * 64 + (c - 64)];
      Wct[j] = f2bf(v);
    } else if (i < 34816) {
      int j = i - 32768; int n = j >> 6, k = j & 63;
      Wp2t[j] = f2bf(Wp2[k * 32 + n]);
    }
  }
  for (int k = t; k < NBUK; k += 256) { hd[k] = 0; hs[k] = 0; }
  __syncthreads();
  int chunk = (E + NBLK - 1) / NBLK;
  int start = blk * chunk, end = min(E, start + chunk);
  for (int i = start + t; i < end; i += 256) {
    atomicAdd(&hd[dst[i] >> 8], 1);
    atomicAdd(&hs[src[i] >> 8], 1);
  }
  __syncthreads();
  for (int k = t; k < NBUK; k += 256) {
    grams[k * NBLK + blk] = hd[k];
    grams[GRD + k * NBLK + blk] = hs[k];
  }
}

__global__ __launch_bounds__(256) void k_gscan1(const int* __restrict__ g,
                                                int* __restrict__ bsum) {
  __shared__ int lds[256];
  int b = blockIdx.x, t = threadIdx.x;
  int base = b * 1024 + t * 4;
  int s = g[base] + g[base + 1] + g[base + 2] + g[base + 3];
  lds[t] = s; __syncthreads();
  for (int st = 128; st > 0; st >>= 1) {
    if (t < st) lds[t] += lds[t + st];
    __syncthreads();
  }
  if (t == 0) bsum[b] = lds[0];
}

__global__ __launch_bounds__(256) void k_gscan3(int* __restrict__ g,
                                                const int* __restrict__ bsum) {
  __shared__ int lds[256], lds2[256];
  int b = blockIdx.x, t = threadIdx.x;
  int bv = bsum[t];
  lds2[t] = bv; __syncthreads();
  for (int st = 1; st < 256; st <<= 1) {
    int add = (t >= st) ? lds2[t - st] : 0;
    __syncthreads();
    lds2[t] += add;
    __syncthreads();
  }
  int bpref = (b > 0) ? lds2[b - 1] : 0;

  int base = b * 1024 + t * 4;
  int v[4]; int s = 0;
#pragma unroll
  for (int j = 0; j < 4; j++) { v[j] = g[base + j]; s += v[j]; }
  lds[t] = s; __syncthreads();
  int mine = s;
  for (int st = 1; st < 256; st <<= 1) {
    int add = (t >= st) ? lds[t - st] : 0;
    __syncthreads();
    lds[t] += add;
    __syncthreads();
  }
  int excl = lds[t] - mine + bpref;
#pragma unroll
  for (int j = 0; j < 4; j++) { g[base + j] = excl; excl += v[j]; }
}

__global__ __launch_bounds__(256) void k_part(
    const int* __restrict__ src, const int* __restrict__ dst,
    const int* __restrict__ grams, unsigned* __restrict__ pdst,
    unsigned char* __restrict__ sbuf, int E) {
  __shared__ int curd[NBUK], curs[NBUK];
  int blk = blockIdx.x, t = threadIdx.x;
  for (int k = t; k < NBUK; k += 256) {
    curd[k] = grams[k * NBLK + blk];
    curs[k] = grams[GRD + k * NBLK + blk] - E;
  }
  __syncthreads();
  int chunk = (E + NBLK - 1) / NBLK;
  int start = blk * chunk, end = min(E, start + chunk);
  for (int i = start + t; i < end; i += 256) {
    int s = src[i], d = dst[i];
    int pd = atomicAdd(&curd[d >> 8], 1);
    pdst[pd] = ((unsigned)s << 8) | (unsigned)(d & 255);
    int ps = atomicAdd(&curs[s >> 8], 1);
    sbuf[ps] = (unsigned char)(s & 255);
  }
}

// ---- dcsr body (slim): adj, rowst, rin, rout --------------------------------
__device__ __forceinline__ void dcsr_body(
    const unsigned* __restrict__ pdst, const unsigned char* __restrict__ sbuf,
    const int* __restrict__ grams,
    int* __restrict__ adj, int* __restrict__ rowst,
    float* __restrict__ rin, float* __restrict__ rout, int N, int E, int b) {
  __shared__ int hist[256], cur[256];
  int t = threadIdx.x;
  int base = grams[b * 256];
  int end  = grams[b * 256 + 256];
  hist[t] = 0; __syncthreads();
  for (int i = base + t; i < end; i += 256)
    atomicAdd(&hist[pdst[i] & 255], 1);
  __syncthreads();
  int cnt = hist[t];
  for (int st = 1; st < 256; st <<= 1) {
    int add = (t >= st) ? hist[t - st] : 0;
    __syncthreads();
    hist[t] += add;
    __syncthreads();
  }
  int excl = hist[t] - cnt;
  cur[t] = excl;
  int node = b * 256 + t;
  if (node < N) {
    rowst[node] = base + excl;
    rin[node] = rsqrtf((float)max(cnt, 1));
  }
  __syncthreads();
  for (int i = base + t; i < end; i += 256) {
    unsigned u = pdst[i];
    int pos = base + atomicAdd(&cur[u & 255], 1);
    adj[pos] = (int)(u >> 8);
  }
  __syncthreads();
  hist[t] = 0; __syncthreads();
  int sb = grams[GRD + b * 256] - E;
  int se = grams[GRD + b * 256 + 256] - E;
  for (int i = sb + t; i < se; i += 256)
    atomicAdd(&hist[sbuf[i]], 1);
  __syncthreads();
  if (node < N) rout[node] = rsqrtf((float)max(hist[t], 1));
}

// ---- MFMA GEMM body: C_bf16[M,BN] = (A[M,K]*scale[M]?) @ W, Wt bf16 [BN][K] -
template <int K, int BN, bool ABF, bool SC>
__device__ __forceinline__ void gemm_body(
    const void* __restrict__ Av, const float* __restrict__ scale,
    const unsigned short* __restrict__ Wt, unsigned short* __restrict__ C,
    int M, int bid) {
  constexpr int KP = K + 8;
  __shared__ __attribute__((aligned(16))) unsigned short As[64][KP];
  __shared__ __attribute__((aligned(16))) unsigned short Ws[BN][KP];
  int tid = threadIdx.x;
  int row0 = bid * 64;

  for (int i = tid; i < BN * K / 8; i += 256) {
    int n = i / (K / 8), seg = i % (K / 8);
    *(uint4*)&Ws[n][seg * 8] = ((const uint4*)Wt)[i];
  }
  {
    constexpr int CH = K / 4;
    int r = tid >> 2, q = tid & 3;
    int row = row0 + r;
    if (row < M) {
      float sc = SC ? scale[row] : 1.0f;
      if constexpr (!ABF) {
        const float4* ap = (const float4*)((const float*)Av + (size_t)row * K + q * CH);
#pragma unroll
        for (int c = 0; c < CH / 8; c++) {
          float4 v0 = ap[2 * c], v1 = ap[2 * c + 1];
          uint4 o;
          o.x = packbf2(v0.x * sc, v0.y * sc);
          o.y = packbf2(v0.z * sc, v0.w * sc);
          o.z = packbf2(v1.x * sc, v1.y * sc);
          o.w = packbf2(v1.z * sc, v1.w * sc);
          *(uint4*)&As[r][q * CH + c * 8] = o;
        }
      } else {
        const uint4* ap = (const uint4*)((const unsigned short*)Av + (size_t)row * K + q * CH);
#pragma unroll
        for (int c = 0; c < CH / 8; c++) {
          uint4 v = ap[c];
          if constexpr (SC) {
            uint4 o;
            o.x = packbf2(bl(v.x) * sc, bh(v.x) * sc);
            o.y = packbf2(bl(v.y) * sc, bh(v.y) * sc);
            o.z = packbf2(bl(v.z) * sc, bh(v.z) * sc);
            o.w = packbf2(bl(v.w) * sc, bh(v.w) * sc);
            *(uint4*)&As[r][q * CH + c * 8] = o;
          } else {
            *(uint4*)&As[r][q * CH + c * 8] = v;
          }
        }
      }
    } else {
#pragma unroll
      for (int c = 0; c < CH / 8; c++)
        *(uint4*)&As[r][q * CH + c * 8] = make_uint4(0, 0, 0, 0);
    }
  }
  __syncthreads();

  constexpr int KS = K / 32;
  constexpr int NT = BN / 16;
  int wav = tid >> 6, lane = tid & 63;
  int quad = lane >> 4, lrow = lane & 15;
  int mb = wav * 16;

  bf16x8 af[KS];
#pragma unroll
  for (int s = 0; s < KS; s++)
    af[s] = *(const bf16x8*)&As[mb + lrow][s * 32 + quad * 8];

  f32x4 acc[NT];
#pragma unroll
  for (int nt = 0; nt < NT; nt++) acc[nt] = (f32x4){0.f, 0.f, 0.f, 0.f};
#pragma unroll
  for (int nt = 0; nt < NT; nt++) {
#pragma unroll
    for (int s = 0; s < KS; s++) {
      bf16x8 bf = *(const bf16x8*)&Ws[nt * 16 + lrow][s * 32 + quad * 8];
      acc[nt] = __builtin_amdgcn_mfma_f32_16x16x32_bf16(af[s], bf, acc[nt], 0, 0, 0);
    }
  }
#pragma unroll
  for (int nt = 0; nt < NT; nt++) {
#pragma unroll
    for (int reg = 0; reg < 4; reg++) {
      int row = row0 + mb + quad * 4 + reg;
      if (row < M) C[(size_t)row * BN + nt * 16 + lrow] = f2bf(acc[nt][reg]);
    }
  }
}

template <int K, int BN, bool ABF, bool SC>
__global__ __launch_bounds__(256) void k_gemm(
    const void* __restrict__ Av, const float* __restrict__ scale,
    const unsigned short* __restrict__ Wt, unsigned short* __restrict__ C, int M) {
  gemm_body<K, BN, ABF, SC>(Av, scale, Wt, C, M, blockIdx.x);
}

// ---- fused gemm1 + dcsr (independent work, one launch) ----------------------
__global__ __launch_bounds__(256) void k_gdc(
    const float* __restrict__ x, const unsigned short* __restrict__ W1t,
    unsigned short* __restrict__ h0, int M, int ngb,
    const unsigned* __restrict__ pdst, const unsigned char* __restrict__ sbuf,
    const int* __restrict__ grams, int* __restrict__ adj, int* __restrict__ rowst,
    float* __restrict__ rin, float* __restrict__ rout, int N, int E) {
  if ((int)blockIdx.x < ngb)
    gemm_body<128, 128, false, false>(x, nullptr, W1t, h0, M, blockIdx.x);
  else
    dcsr_body(pdst, sbuf, grams, adj, rowst, rin, rout, N, E,
              (int)blockIdx.x - ngb);
}

// ---- aggregation: TPN threads per node, each owns a uint4 (8 bf16) chunk ----
// RS: scale each gathered row by rout[src] (broadcast-coalesced 4B load).
template <int F, bool RS>
__global__ __launch_bounds__(256) void k_agg(
    const unsigned short* __restrict__ hin, const int* __restrict__ rowst,
    const int* __restrict__ adj, const float* __restrict__ rin,
    const float* __restrict__ rout, const float* __restrict__ bias,
    unsigned short* __restrict__ hout, int N, int E, int do_relu) {
  constexpr int TPN = F / 8;
  constexpr int NPB = 256 / TPN;
  int node = blockIdx.x * NPB + threadIdx.x / TPN;
  int c = threadIdx.x % TPN;
  if (node >= N) return;
  int start = rowst[node];
  int end = (node + 1 < N) ? rowst[node + 1] : E;
  const uint4* h4 = (const uint4*)hin;

  float a[8], b[8];
#pragma unroll
  for (int j = 0; j < 8; j++) { a[j] = 0.f; b[j] = 0.f; }

  int i = start;
  for (; i + 3 < end; i += 4) {
    int u0 = adj[i], u1 = adj[i + 1], u2 = adj[i + 2], u3 = adj[i + 3];
    float r0 = RS ? rout[u0] : 1.0f;
    float r1 = RS ? rout[u1] : 1.0f;
    float r2 = RS ? rout[u2] : 1.0f;
    float r3 = RS ? rout[u3] : 1.0f;
    uint4 w0 = h4[(size_t)u0 * TPN + c];
    uint4 w1 = h4[(size_t)u1 * TPN + c];
    uint4 w2 = h4[(size_t)u2 * TPN + c];
    uint4 w3 = h4[(size_t)u3 * TPN + c];
    a[0] = fmaf(r0, bl(w0.x), a[0]); a[1] = fmaf(r0, bh(w0.x), a[1]);
    a[2] = fmaf(r0, bl(w0.y), a[2]); a[3] = fmaf(r0, bh(w0.y), a[3]);
    a[4] = fmaf(r0, bl(w0.z), a[4]); a[5] = fmaf(r0, bh(w0.z), a[5]);
    a[6] = fmaf(r0, bl(w0.w), a[6]); a[7] = fmaf(r0, bh(w0.w), a[7]);
    b[0] = fmaf(r1, bl(w1.x), b[0]); b[1] = fmaf(r1, bh(w1.x), b[1]);
    b[2] = fmaf(r1, bl(w1.y), b[2]); b[3] = fmaf(r1, bh(w1.y), b[3]);
    b[4] = fmaf(r1, bl(w1.z), b[4]); b[5] = fmaf(r1, bh(w1.z), b[5]);
    b[6] = fmaf(r1, bl(w1.w), b[6]); b[7] = fmaf(r1, bh(w1.w), b[7]);
    a[0] = fmaf(r2, bl(w2.x), a[0]); a[1] = fmaf(r2, bh(w2.x), a[1]);
    a[2] = fmaf(r2, bl(w2.y), a[2]); a[3] = fmaf(r2, bh(w2.y), a[3]);
    a[4] = fmaf(r2, bl(w2.z), a[4]); a[5] = fmaf(r2, bh(w2.z), a[5]);
    a[6] = fmaf(r2, bl(w2.w), a[6]); a[7] = fmaf(r2, bh(w2.w), a[7]);
    b[0] = fmaf(r3, bl(w3.x), b[0]); b[1] = fmaf(r3, bh(w3.x), b[1]);
    b[2] = fmaf(r3, bl(w3.y), b[2]); b[3] = fmaf(r3, bh(w3.y), b[3]);
    b[4] = fmaf(r3, bl(w3.z), b[4]); b[5] = fmaf(r3, bh(w3.z), b[5]);
    b[6] = fmaf(r3, bl(w3.w), b[6]); b[7] = fmaf(r3, bh(w3.w), b[7]);
  }
  for (; i < end; i++) {
    int u0 = adj[i];
    float r0 = RS ? rout[u0] : 1.0f;
    uint4 w0 = h4[(size_t)u0 * TPN + c];
    a[0] = fmaf(r0, bl(w0.x), a[0]); a[1] = fmaf(r0, bh(w0.x), a[1]);
    a[2] = fmaf(r0, bl(w0.y), a[2]); a[3] = fmaf(r0, bh(w0.y), a[3]);
    a[4] = fmaf(r0, bl(w0.z), a[4]); a[5] = fmaf(r0, bh(w0.z), a[5]);
    a[6] = fmaf(r0, bl(w0.w), a[6]); a[7] = fmaf(r0, bh(w0.w), a[7]);
  }
  float r = rin[node];
  const float4* bp = (const float4*)(bias + c * 8);
  float4 bb0 = bp[0], bb1 = bp[1];
  float o0 = fmaf(a[0] + b[0], r, bb0.x);
  float o1 = fmaf(a[1] + b[1], r, bb0.y);
  float o2 = fmaf(a[2] + b[2], r, bb0.z);
  float o3 = fmaf(a[3] + b[3], r, bb0.w);
  float o4 = fmaf(a[4] + b[4], r, bb1.x);
  float o5 = fmaf(a[5] + b[5], r, bb1.y);
  float o6 = fmaf(a[6] + b[6], r, bb1.z);
  float o7 = fmaf(a[7] + b[7], r, bb1.w);
  if (do_relu) {
    o0 = fmaxf(o0, 0.f); o1 = fmaxf(o1, 0.f); o2 = fmaxf(o2, 0.f);
    o3 = fmaxf(o3, 0.f); o4 = fmaxf(o4, 0.f); o5 = fmaxf(o5, 0.f);
    o6 = fmaxf(o6, 0.f); o7 = fmaxf(o7, 0.f);
  }
  uint4 o;
  o.x = packbf2(o0, o1); o.y = packbf2(o2, o3);
  o.z = packbf2(o4, o5); o.w = packbf2(o6, o7);
  ((uint4*)hout)[(size_t)node * TPN + c] = o;
}

// ---- per-edge MLP, original order, coalesced NONTEMPORAL out writes ---------
__global__ __launch_bounds__(256) void k_edge(
    const unsigned short* __restrict__ ab, const int* __restrict__ src,
    const int* __restrict__ dst,
    const unsigned short* __restrict__ Wp2t, const float* __restrict__ bp1,
    const float* __restrict__ bp2, const float* __restrict__ Wp3,
    const float* __restrict__ bp3, float* __restrict__ out, int E) {
  __shared__ __attribute__((aligned(16))) unsigned short z1s[128][72];
  __shared__ __attribute__((aligned(16))) unsigned short w2t[32][72];
  __shared__ float sb1[64], sb2[32], sw3[32];

  int t = threadIdx.x;
  {
    uint4 v = ((const uint4*)Wp2t)[t];
    int n = t >> 3, seg = t & 7;
    *(uint4*)&w2t[n][seg * 8] = v;
    if (t < 64) sb1[t] = bp1[t];
    else if (t < 96) sb2[t - 64] = bp2[t - 64];
    else if (t < 128) sw3[t - 96] = Wp3[t - 96];
  }
  __syncthreads();

  int p0 = blockIdx.x * 128;
  {
    int m = t >> 1, half = t & 1, p = p0 + m;
    int s = 0, d = 0;
    if (p < E) { s = src[p]; d = dst[p]; }
    const uint4* apf = (const uint4*)(ab + (size_t)s * 128 + half * 32);
    const uint4* bpf = (const uint4*)(ab + (size_t)d * 128 + 64 + half * 32);
    int jb = half * 32;
#pragma unroll
    for (int q = 0; q < 4; q++) {
      uint4 av = apf[q], bv = bpf[q];
      int j = jb + 8 * q;
      float z0 = fmaxf(bl(av.x) + bl(bv.x) + sb1[j + 0], 0.f);
      float z1 = fmaxf(bh(av.x) + bh(bv.x) + sb1[j + 1], 0.f);
      float z2 = fmaxf(bl(av.y) + bl(bv.y) + sb1[j + 2], 0.f);
      float z3 = fmaxf(bh(av.y) + bh(bv.y) + sb1[j + 3], 0.f);
      float z4 = fmaxf(bl(av.z) + bl(bv.z) + sb1[j + 4], 0.f);
      float z5 = fmaxf(bh(av.z) + bh(bv.z) + sb1[j + 5], 0.f);
      float z6 = fmaxf(bl(av.w) + bl(bv.w) + sb1[j + 6], 0.f);
      float z7 = fmaxf(bh(av.w) + bh(bv.w) + sb1[j + 7], 0.f);
      uint4 o;
      o.x = packbf2(z0, z1); o.y = packbf2(z2, z3);
      o.z = packbf2(z4, z5); o.w = packbf2(z6, z7);
      *(uint4*)&z1s[m][j] = o;
    }
  }
  __syncthreads();

  int wav = t >> 6, lane = t & 63;
  int quad = lane >> 4, lrow = lane & 15;

  bf16x8 bfr[2][2];
#pragma unroll
  for (int s = 0; s < 2; s++)
#pragma unroll
    for (int nt = 0; nt < 2; nt++)
      bfr[s][nt] = *(const bf16x8*)&w2t[nt * 16 + lrow][s * 32 + quad * 8];

  f32x4 acc[2][2];
#pragma unroll
  for (int mt = 0; mt < 2; mt++)
#pragma unroll
    for (int nt = 0; nt < 2; nt++) acc[mt][nt] = (f32x4){0.f, 0.f, 0.f, 0.f};

#pragma unroll
  for (int mt = 0; mt < 2; mt++) {
    int mb = (wav * 2 + mt) * 16;
#pragma unroll
    for (int s = 0; s < 2; s++) {
      bf16x8 a = *(const bf16x8*)&z1s[mb + lrow][s * 32 + quad * 8];
#pragma unroll
      for (int nt = 0; nt < 2; nt++)
        acc[mt][nt] = __builtin_amdgcn_mfma_f32_16x16x32_bf16(a, bfr[s][nt], acc[mt][nt], 0, 0, 0);
    }
  }

  float bb0 = sb2[lrow], bb1 = sb2[16 + lrow];
  float w30 = sw3[lrow], w31 = sw3[16 + lrow];
  float p2[2][4];
#pragma unroll
  for (int mt = 0; mt < 2; mt++)
#pragma unroll
    for (int reg = 0; reg < 4; reg++)
      p2[mt][reg] = fmaxf(acc[mt][0][reg] + bb0, 0.f) * w30 +
                    fmaxf(acc[mt][1][reg] + bb1, 0.f) * w31;
#pragma unroll
  for (int off = 1; off < 16; off <<= 1) {
#pragma unroll
    for (int mt = 0; mt < 2; mt++)
#pragma unroll
      for (int reg = 0; reg < 4; reg++)
        p2[mt][reg] += __shfl_xor(p2[mt][reg], off, 64);
  }
  if (lrow < 4) {
    float b3 = bp3[0];
#pragma unroll
    for (int mt = 0; mt < 2; mt++) {
      float score = p2[mt][0];
      if (lrow == 1) score = p2[mt][1];
      if (lrow == 2) score = p2[mt][2];
      if (lrow == 3) score = p2[mt][3];
      score += b3;
      int pp = p0 + (wav * 2 + mt) * 16 + quad * 4 + lrow;
      if (pp < E)
        __builtin_nontemporal_store(1.0f / (1.0f + __expf(-score)), &out[pp]);
    }
  }
}

extern "C" void kernel_launch(void* const* d_in, const int* in_sizes, int n_in,
                              void* d_out, int out_size, void* d_ws, size_t ws_size,
                              hipStream_t stream) {
  const float* x   = (const float*)d_in[0];
  const int*   src = (const int*)d_in[1];
  const int*   dst = (const int*)d_in[2];
  const float* W1  = (const float*)d_in[3];
  const float* b1  = (const float*)d_in[4];
  const float* W2  = (const float*)d_in[5];
  const float* b2  = (const float*)d_in[6];
  const float* Wp1 = (const float*)d_in[7];
  const float* bp1 = (const float*)d_in[8];
  const float* Wp2 = (const float*)d_in[9];
  const float* bp2 = (const float*)d_in[10];
  const float* Wp3 = (const float*)d_in[11];
  const float* bp3 = (const float*)d_in[12];
  float* out = (float*)d_out;

  int N = in_sizes[0] / 128;
  int E = in_sizes[1];

  char* w = (char*)d_ws;
  // pdst/sbuf NO LONGER alias bufA: dcsr (reads pdst) is fused with gemm1
  // (writes bufA) in one concurrent launch.
  unsigned short* bufA = (unsigned short*)w; w += (size_t)N * 128 * 2;
  unsigned short* bufB = (unsigned short*)w; w += (size_t)N * 128 * 2;
  unsigned* pdst = (unsigned*)w;             w += (size_t)E * 4;
  unsigned char* sbuf = (unsigned char*)w;   w += (size_t)E;
  w = (char*)(((size_t)w + 255) & ~(size_t)255);
  int* grams  = (int*)w;    w += (size_t)GRT * sizeof(int);
  int* bsum   = (int*)w;    w += 256 * sizeof(int);
  int* rowst  = (int*)w;    w += (size_t)N * sizeof(int);
  int* adj    = (int*)w;    w += (size_t)E * sizeof(int);
  float* rin  = (float*)w;  w += (size_t)N * sizeof(float);
  float* rout = (float*)w;  w += (size_t)N * sizeof(float);
  unsigned short* W1t  = (unsigned short*)w; w += 16384 * 2;
  unsigned short* W2t  = (unsigned short*)w; w += 8192 * 2;
  unsigned short* Wct  = (unsigned short*)w; w += 8192 * 2;
  unsigned short* Wp2t = (unsigned short*)w; w += 2048 * 2;

  int nbk = (N + 255) / 256;   // 391 dcsr buckets
  int ngb = (N + 63) / 64;     // 1563 gemm1 blocks

  // ---- CSR build + weight prep ----
  k_hist<<<NBLK, 256, 0, stream>>>(src, dst, grams, E, W1, W2, Wp1, Wp2,
                                   W1t, W2t, Wct, Wp2t);
  k_gscan1<<<GRT / 1024, 256, 0, stream>>>(grams, bsum);
  k_gscan3<<<GRT / 1024, 256, 0, stream>>>(grams, bsum);
  k_part<<<NBLK, 256, 0, stream>>>(src, dst, grams, pdst, sbuf, E);

  // ---- fused: gemm1 (h0 = bf16(x@W1), rout deferred) + dcsr ----
  k_gdc<<<ngb + nbk, 256, 0, stream>>>(x, W1t, bufA, N, ngb,
                                       pdst, sbuf, grams, adj, rowst,
                                       rin, rout, N, E);
  // h1 = relu(Agg(rout[u]*h0[u])*rin + b1) -> bufB [N,128]
  k_agg<128, true><<<(N + 15) / 16, 256, 0, stream>>>(
      bufA, rowst, adj, rin, rout, b1, bufB, N, E, 1);
  // h2p = bf16((h1*rout)@W2) -> bufA [N,64]
  k_gemm<128, 64, true, true><<<(N + 63) / 64, 256, 0, stream>>>(
      bufB, rout, W2t, bufA, N);
  // h = Agg(h2p)*rin + b2 -> bufB [N,64]
  k_agg<64, false><<<(N + 31) / 32, 256, 0, stream>>>(
      bufA, rowst, adj, rin, rout, b2, bufB, N, E, 0);
  // ab = bf16(h @ Wc) -> bufA [N,128]
  k_gemm<64, 128, true, false><<<(N + 63) / 64, 256, 0, stream>>>(
      bufB, nullptr, Wct, bufA, N);
  // edge MLP + sigmoid, original order, NT coalesced out
  k_edge<<<(E + 127) / 128, 256, 0, stream>>>(bufA, src, dst, Wp2t,
                                              bp1, bp2, Wp3, bp3, out, E);
}